// Round 7
// baseline (171.761 us; speedup 1.0000x reference)
//
#include <hip/hip_runtime.h>
#include <stdint.h>

#define Bv 16
#define Sv 512
#define Hv 12
#define Dv 64
#define HIDv 768

typedef __attribute__((ext_vector_type(8))) short bf8_t;
typedef __attribute__((ext_vector_type(4))) float f32x4;
typedef __attribute__((ext_vector_type(8))) unsigned short u16x8;
typedef __attribute__((ext_vector_type(4))) unsigned short u16x4;

__device__ __forceinline__ float b2f(unsigned short u){
    union { unsigned int i; float f; } x; x.i = ((unsigned int)u) << 16; return x.f;
}
__device__ __forceinline__ unsigned short f2b(float f){
    union { float f; unsigned int i; } x; x.f = f;
    unsigned int r = x.i + 0x7fff + ((x.i >> 16) & 1);
    return (unsigned short)(r >> 16);
}
__device__ __forceinline__ void gload16(const unsigned short* g, unsigned short* l){
    __builtin_amdgcn_global_load_lds(
        (const __attribute__((address_space(1))) void*)g,
        (__attribute__((address_space(3))) void*)l, 16, 0, 0);
}

#define RS 0.18033688f          /* 0.125 * log2(e) */
#define LOG2E 1.44269504f

// ---------------------------------------------------------------------------
__global__ void cvt_bf16(const float* __restrict__ src, unsigned short* __restrict__ dst, int n4){
    int i = blockIdx.x * 256 + threadIdx.x;
    int stride = gridDim.x * 256;
    for (; i < n4; i += stride){
        float4 v = ((const float4*)src)[i];
        u16x4 o = { f2b(v.x), f2b(v.y), f2b(v.z), f2b(v.w) };
        ((u16x4*)dst)[i] = o;
    }
}

__global__ void cvt_w3(const float* __restrict__ a, const float* __restrict__ b,
                       const float* __restrict__ c, unsigned short* __restrict__ dst, int n4each){
    int i = blockIdx.x * 256 + threadIdx.x;
    if (i >= 3*n4each) return;
    int which = i / n4each, j = i - which*n4each;
    const float* src = which == 0 ? a : (which == 1 ? b : c);
    float4 v = ((const float4*)src)[j];
    u16x4 o = { f2b(v.x), f2b(v.y), f2b(v.z), f2b(v.w) };
    ((u16x4*)dst)[i] = o;
}

// ---------------------------------------------------------------------------
// lvl bias pre-tiled to the attn fragment layout (verified R6).
// ---------------------------------------------------------------------------
__global__ __launch_bounds__(256) void prep_bias_t(
    const int* __restrict__ cmat, const int* __restrict__ wmat,
    const float* __restrict__ mask, const float* __restrict__ ce, const float* __restrict__ we,
    unsigned short* __restrict__ lvlt)
{
    __shared__ float tab[64];
    __shared__ float mrow[64];
    const int t = threadIdx.x;
    const int blk = blockIdx.x;
    const int c8 = blk & 7, lt = (blk >> 3) & 7, b = blk >> 6;
    if (t < 64) tab[t] = (0.5f*ce[t>>3] + 0.5f*we[t&7]) * RS;
    if (t >= 64 && t < 128) mrow[t-64] = mask[b*512 + c8*64 + (t-64)] * LOG2E;
    __syncthreads();
    const int w = t >> 6, lane = t & 63, g = lane >> 4, cc = lane & 15;
    const int llb = lt*64 + w*16 + g*4;
    const int rlb = c8*64 + cc;
    unsigned short o[16];
    #pragma unroll
    for (int reg = 0; reg < 4; ++reg){
        const int* cr = cmat + ((size_t)b*512 + llb + reg)*512 + rlb;
        const int* wr = wmat + ((size_t)b*512 + llb + reg)*512 + rlb;
        #pragma unroll
        for (int i = 0; i < 4; ++i){
            int cv = cr[i*16], wv = wr[i*16];
            o[reg*4 + i] = f2b(tab[(cv<<3)|wv] + mrow[i*16 + cc]);
        }
    }
    unsigned short* dst = lvlt + ((size_t)blk*256 + t)*16;
    *(u16x8*)dst       = *(u16x8*)&o[0];
    *(u16x8*)(dst + 8) = *(u16x8*)&o[8];
}

// ---------------------------------------------------------------------------
// QKV projection (verified): Q,K -> [proj][b][h][s][d], V -> [b][h][d][s]
// ---------------------------------------------------------------------------
__global__ __launch_bounds__(256,3) void qkv_gemm(
    const unsigned short* __restrict__ Xb,
    const unsigned short* __restrict__ Wb,
    const float* __restrict__ bq, const float* __restrict__ bk, const float* __restrict__ bv,
    unsigned short* __restrict__ qkb,
    unsigned short* __restrict__ vtb)
{
    __shared__ unsigned short Ab[128*40];
    __shared__ unsigned short Bb[128*40];
    const int t = threadIdx.x;
    const int w = t >> 6, lane = t & 63, g = lane >> 4, cc = lane & 15;
    const int wm = w >> 1, wn = w & 1;
    const int m0 = blockIdx.x * 128;
    const int n0 = blockIdx.y * 128;

    const f32x4 fz = {0.f,0.f,0.f,0.f};
    f32x4 acc[4][4];
    #pragma unroll
    for (int i = 0; i < 4; ++i)
        #pragma unroll
        for (int j = 0; j < 4; ++j) acc[i][j] = fz;

    u16x8 pa[2], pb[2];
    #pragma unroll
    for (int r = 0; r < 2; ++r){
        int chunk = t + r*256; int row = chunk >> 2; int ch = chunk & 3;
        pa[r] = *(const u16x8*)(Xb + (size_t)(m0+row)*768 + ch*8);
        pb[r] = *(const u16x8*)(Wb + (size_t)(n0+row)*768 + ch*8);
    }
    for (int k0 = 0; k0 < 768; k0 += 32){
        __syncthreads();
        #pragma unroll
        for (int r = 0; r < 2; ++r){
            int chunk = t + r*256; int row = chunk >> 2; int ch = chunk & 3;
            *(u16x8*)&Ab[row*40 + ch*8] = pa[r];
            *(u16x8*)&Bb[row*40 + ch*8] = pb[r];
        }
        __syncthreads();
        if (k0 + 32 < 768){
            #pragma unroll
            for (int r = 0; r < 2; ++r){
                int chunk = t + r*256; int row = chunk >> 2; int ch = chunk & 3;
                pa[r] = *(const u16x8*)(Xb + (size_t)(m0+row)*768 + (k0+32) + ch*8);
                pb[r] = *(const u16x8*)(Wb + (size_t)(n0+row)*768 + (k0+32) + ch*8);
            }
        }
        bf8_t af[4], bfr[4];
        #pragma unroll
        for (int mf = 0; mf < 4; ++mf)
            af[mf] = *(const bf8_t*)&Ab[(wm*64 + mf*16 + cc)*40 + g*8];
        #pragma unroll
        for (int nf = 0; nf < 4; ++nf)
            bfr[nf] = *(const bf8_t*)&Bb[(wn*64 + nf*16 + cc)*40 + g*8];
        #pragma unroll
        for (int mf = 0; mf < 4; ++mf)
            #pragma unroll
            for (int nf = 0; nf < 4; ++nf)
                acc[mf][nf] = __builtin_amdgcn_mfma_f32_16x16x32_bf16(af[mf], bfr[nf], acc[mf][nf], 0,0,0);
    }

    const int b  = m0 >> 9;
    const int s0 = (m0 & 511) + wm*64;
    const int nbase = n0 + wn*64;
    const int proj = nbase / 768;
    const int nin0 = nbase % 768;
    const float* bias = proj == 0 ? bq : (proj == 1 ? bk : bv);
    #pragma unroll
    for (int nf = 0; nf < 4; ++nf){
        int nin = nin0 + nf*16 + cc;
        int h = nin >> 6, d = nin & 63;
        float bvv = bias[nin];
        #pragma unroll
        for (int mf = 0; mf < 4; ++mf){
            int s = s0 + mf*16 + g*4;
            if (proj < 2){
                unsigned short* base = qkb + (((((size_t)proj*Bv + b)*Hv + h)*Sv + s)*Dv + d);
                #pragma unroll
                for (int r2 = 0; r2 < 4; ++r2)
                    base[(size_t)r2*Dv] = f2b(acc[mf][nf][r2] + bvv);
            } else {
                u16x4 o = { f2b(acc[mf][nf][0]+bvv), f2b(acc[mf][nf][1]+bvv),
                            f2b(acc[mf][nf][2]+bvv), f2b(acc[mf][nf][3]+bvv) };
                *(u16x4*)(vtb + ((((size_t)b*Hv + h)*Dv + d)*Sv + s)) = o;
            }
        }
    }
}

// ---------------------------------------------------------------------------
// Fused attention v7:
//  - DE fragments loaded straight from global (L2-resident, XCD-pinned);
//    des LDS buffer + stage_de gone (-16KB, -20 b128 LDS reads/wave).
//  - T1/T2 share d-frags: wave w computes T2 for rl-block (3-w) whose jb set
//    equals T1's {w..w+4}; kf captured free from QK loop at i==3-w.
//  - band buffers [rl][ll]: t1c f32 stride68 (b128 gathers), t2c bf16
//    stride68 (b64 gathers).
//  - LDS 49.5KB -> 3 blocks/CU (grid 1536 = 6/CU = two clean rounds).
// ---------------------------------------------------------------------------
__global__ __launch_bounds__(256,2) void attn(
    const unsigned short* __restrict__ qkb,
    const unsigned short* __restrict__ vtb,
    const unsigned short* __restrict__ deb,    // [1024][64] bf16 (row 1023 = pad)
    const unsigned short* __restrict__ lvlt,   // fragment-tiled lvl bias
    float* __restrict__ out)
{
    __shared__ __align__(16) unsigned short sm[25344];
    unsigned short* ks  = sm;                      // [64][64] swz   8192 B
    unsigned short* vsq = sm + 4096;               // [64][64] swz   8192 B
    unsigned short* P   = sm + 8192;               // [64][64] swz   8192 B
    float*          t1c = (float*)(sm + 12288);    // [64][68] f32  17408 B
    unsigned short* t2c = sm + 20992;              // [64][68] bf16  8704 B

    const int t = threadIdx.x, w = t >> 6, lane = t & 63, g = lane >> 4, cc = lane & 15;
    const int lr8 = lane >> 3, lc8 = lane & 7;

    // b-based XCD remap: all blocks of batch b on XCD b%8
    const int wg = blockIdx.x;
    const int xcd = wg & 7, inner = wg >> 3;
    const int b  = ((inner & 1) << 3) | xcd;
    const int r2 = inner >> 1;
    const int h  = r2 % 12, lt = r2 / 12;
    const int l0 = lt * 64;

    const unsigned short* qp = qkb + ((((size_t)0*Bv + b)*Hv + h)*Sv + l0)*Dv;
    const unsigned short* kp = qkb + ((((size_t)1*Bv + b)*Hv + h)*Sv)*Dv;
    const unsigned short* vp = vtb + (((size_t)b*Hv + h)*Dv)*Sv;
    const unsigned short* lvbase = lvlt + (((size_t)b*8 + lt)*8)*256*16 + (size_t)t*16;

    const f32x4 fz = {0.f,0.f,0.f,0.f};
    const int llb = w*16 + g*4;
    const int R   = 3 - w;                 // T2 rl-block handled by this wave
    const int rl2b = R*16 + g*4;

    auto stage_k = [&](int r0){
        #pragma unroll
        for (int j = 0; j < 2; ++j){
            int row = w*16 + j*8 + lr8;
            int ch  = lc8 ^ (row & 7);
            gload16(kp + (size_t)(r0 + row)*64 + ch*8, ks + w*1024 + j*512);
        }
    };
    auto stage_v = [&](int r0){
        #pragma unroll
        for (int j = 0; j < 2; ++j){
            int row = w*16 + j*8 + lr8;
            int ch  = lc8 ^ (row & 7);
            gload16(vp + (size_t)row*512 + r0 + ch*8, vsq + w*1024 + j*512);
        }
    };

    // ---- prologue: Q frags straight from global; stage chunk-0 K/V
    bf8_t qf0, qf1;
    {
        int qrow = w*16 + cc;
        qf0 = *(const bf8_t*)(qp + (size_t)qrow*64 + g*8);
        qf1 = *(const bf8_t*)(qp + (size_t)qrow*64 + (g+4)*8);
    }
    stage_k(0); stage_v(0);
    __syncthreads();

    float l_run[4] = {0.f,0.f,0.f,0.f};
    f32x4 ctx[4] = {fz,fz,fz,fz};

    for (int c8 = 0; c8 < 8; ++c8){
        const int r0 = c8 * 64;
        const int base = l0 - r0 + 448;       // DE band origin (64-aligned, >=0)

        // lvl fragment tile (global; latency hidden under MFMA phase)
        u16x8 lva = *(const u16x8*)(lvbase + (size_t)c8*256*16);
        u16x8 lvb = *(const u16x8*)(lvbase + (size_t)c8*256*16 + 8);

        // ---- MFMA phase ----
        __builtin_amdgcn_s_setprio(1);
        f32x4 accs[4];
        bf8_t kf0, kf1;
        #pragma unroll
        for (int i = 0; i < 4; ++i){                    // S = Q K^T
            int row = i*16 + cc;
            bf8_t b0 = *(const bf8_t*)&ks[row*64 + ((g       ^ (row & 7))*8)];
            bf8_t b1 = *(const bf8_t*)&ks[row*64 + (((g + 4) ^ (row & 7))*8)];
            if (i == R){ kf0 = b0; kf1 = b1; }          // K rows of block 3-w
            f32x4 a = fz;
            a = __builtin_amdgcn_mfma_f32_16x16x32_bf16(qf0, b0, a, 0,0,0);
            a = __builtin_amdgcn_mfma_f32_16x16x32_bf16(qf1, b1, a, 0,0,0);
            accs[i] = a;
        }
        #pragma unroll
        for (int i = 0; i < 5; ++i){                    // band: T1 + T2, shared d-frags
            int jrow = base + (w + i)*16 + cc;          // global DE row, in [0,1023]
            bf8_t d0 = *(const bf8_t*)(deb + (size_t)jrow*64 + g*8);
            bf8_t d1 = *(const bf8_t*)(deb + (size_t)jrow*64 + (g+4)*8);
            f32x4 a1 = fz, a2 = fz;
            a1 = __builtin_amdgcn_mfma_f32_16x16x32_bf16(qf0, d0, a1, 0,0,0);
            a1 = __builtin_amdgcn_mfma_f32_16x16x32_bf16(qf1, d1, a1, 0,0,0);
            a2 = __builtin_amdgcn_mfma_f32_16x16x32_bf16(kf0, d0, a2, 0,0,0);
            a2 = __builtin_amdgcn_mfma_f32_16x16x32_bf16(kf1, d1, a2, 0,0,0);
            #pragma unroll
            for (int reg = 0; reg < 4; ++reg){
                int rl1 = 4*g + reg - 16*i - cc + 63;   // T1: row rl1, col ll
                if (rl1 >= 0 && rl1 < 64) t1c[rl1*68 + llb + reg] = a1[reg];
                int ll2 = 4*g + reg + 16*i + cc - 15;   // T2: row rl2b+reg, col ll2
                if (ll2 >= 0 && ll2 < 64) t2c[(rl2b + reg)*68 + ll2] = f2b(a2[reg]);
            }
        }
        __builtin_amdgcn_s_setprio(0);
        __syncthreads();                                // B3: t2c visible; ks dead

        if (c8 < 7) stage_k(r0 + 64);                   // lands during epilogue+PV

        // ---- epilogue: vector band gathers, combine, exp2, P ----
        f32x4 t1v4[4];
        u16x4 t2v4[4];
        #pragma unroll
        for (int i = 0; i < 4; ++i){
            t1v4[i] = *(const f32x4*)&t1c[(16*i + cc)*68 + llb];
            t2v4[i] = *(const u16x4*)&t2c[(16*i + cc)*68 + llb];
        }
        #pragma unroll
        for (int reg = 0; reg < 4; ++reg){
            int ll = llb + reg;
            float ps = 0.f;
            #pragma unroll
            for (int i = 0; i < 4; ++i){
                float lvv = b2f(reg < 2 ? (unsigned short)lva[reg*4 + i]
                                        : (unsigned short)lvb[(reg-2)*4 + i]);
                float sv = (accs[i][reg] + t1v4[i][reg] + b2f((unsigned short)t2v4[i][reg])) * RS + lvv;
                float p = __builtin_amdgcn_exp2f(sv);
                ps += p;
                int rl = i*16 + cc;
                P[ll*64 + (((rl >> 3) ^ (ll & 7)) << 3) + (rl & 7)] = f2b(p);
            }
            ps += __shfl_xor(ps, 1); ps += __shfl_xor(ps, 2);
            ps += __shfl_xor(ps, 4); ps += __shfl_xor(ps, 8);
            l_run[reg] += ps;
        }

        // ---- PV ----
        __builtin_amdgcn_s_setprio(1);
        #pragma unroll
        for (int kh = 0; kh < 2; ++kh){
            int prow = w*16 + cc;
            bf8_t pf = *(const bf8_t*)&P[prow*64 + (((g + 4*kh) ^ (prow & 7)) << 3)];
            #pragma unroll
            for (int nf = 0; nf < 4; ++nf){
                int vr = nf*16 + cc;
                bf8_t vf = *(const bf8_t*)&vsq[vr*64 + (((g + 4*kh) ^ (vr & 7))*8)];
                ctx[nf] = __builtin_amdgcn_mfma_f32_16x16x32_bf16(pf, vf, ctx[nf], 0,0,0);
            }
        }
        __builtin_amdgcn_s_setprio(0);

        if (c8 < 7){
            __syncthreads();            // B1: PV done; drains stage_k loads
            stage_v(r0 + 64);
            __syncthreads();            // B2: drains V
        }
    }

    #pragma unroll
    for (int nf = 0; nf < 4; ++nf){
        #pragma unroll
        for (int reg = 0; reg < 4; ++reg){
            int ll = llb + reg;
            out[((size_t)b*Sv + l0 + ll)*HIDv + h*64 + nf*16 + cc] = ctx[nf][reg] / l_run[reg];
        }
    }
}

extern "C" void kernel_launch(void* const* d_in, const int* in_sizes, int n_in,
                              void* d_out, int out_size, void* d_ws, size_t ws_size,
                              hipStream_t stream)
{
    const float* hs   = (const float*)d_in[0];
    const float* mask = (const float*)d_in[1];
    const int*   cmat = (const int*)  d_in[2];
    const int*   wmat = (const int*)  d_in[3];
    const float* Wq   = (const float*)d_in[4];
    const float* bq   = (const float*)d_in[5];
    const float* Wk   = (const float*)d_in[6];
    const float* bk   = (const float*)d_in[7];
    const float* Wv   = (const float*)d_in[8];
    const float* bv   = (const float*)d_in[9];
    const float* de   = (const float*)d_in[10];
    const float* ce   = (const float*)d_in[11];
    const float* we   = (const float*)d_in[12];
    float* out = (float*)d_out;

    unsigned short* Xb   = (unsigned short*)d_ws;        // 8192*768
    unsigned short* Wb   = Xb   + 6291456;               // 2304*768
    unsigned short* deb  = Wb   + 1769472;               // 1023*64 (+ pad row)
    unsigned short* qkb  = deb  + 65536;                 // 2*16*12*512*64
    unsigned short* vtb  = qkb  + 12582912;              // 16*12*64*512
    unsigned short* lvlt = vtb  + 6291456;               // 1024*256*16

    cvt_bf16<<<2048, 256, 0, stream>>>(hs, Xb, 1572864);
    cvt_w3<<<1728, 256, 0, stream>>>(Wq, Wk, Wv, Wb, 147456);
    cvt_bf16<<<64,   256, 0, stream>>>(de, deb, 16368);
    prep_bias_t<<<1024, 256, 0, stream>>>(cmat, wmat, mask, ce, we, lvlt);

    qkv_gemm<<<dim3(64, 18), 256, 0, stream>>>(Xb, Wb, bq, bk, bv, qkb, vtb);
    attn<<<1536, 256, 0, stream>>>(qkb, vtb, deb, lvlt, out);
}

// Round 8
// 145.291 us; speedup vs baseline: 1.1822x; 1.1822x over previous
//
#include <hip/hip_runtime.h>
#include <stdint.h>

#define Bv 16
#define Sv 512
#define Hv 12
#define Dv 64
#define HIDv 768

typedef __attribute__((ext_vector_type(8))) short bf8_t;
typedef __attribute__((ext_vector_type(4))) float f32x4;
typedef __attribute__((ext_vector_type(8))) unsigned short u16x8;
typedef __attribute__((ext_vector_type(4))) unsigned short u16x4;

__device__ __forceinline__ float b2f(unsigned short u){
    union { unsigned int i; float f; } x; x.i = ((unsigned int)u) << 16; return x.f;
}
__device__ __forceinline__ unsigned short f2b(float f){
    union { float f; unsigned int i; } x; x.f = f;
    unsigned int r = x.i + 0x7fff + ((x.i >> 16) & 1);
    return (unsigned short)(r >> 16);
}
__device__ __forceinline__ void gload16(const unsigned short* g, unsigned short* l){
    __builtin_amdgcn_global_load_lds(
        (const __attribute__((address_space(1))) void*)g,
        (__attribute__((address_space(3))) void*)l, 16, 0, 0);
}

#define RS 0.18033688f          /* 0.125 * log2(e) */
#define LOG2E 1.44269504f

// ---------------------------------------------------------------------------
__global__ void cvt_bf16(const float* __restrict__ src, unsigned short* __restrict__ dst, int n4){
    int i = blockIdx.x * 256 + threadIdx.x;
    int stride = gridDim.x * 256;
    for (; i < n4; i += stride){
        float4 v = ((const float4*)src)[i];
        u16x4 o = { f2b(v.x), f2b(v.y), f2b(v.z), f2b(v.w) };
        ((u16x4*)dst)[i] = o;
    }
}

__global__ void cvt_w3(const float* __restrict__ a, const float* __restrict__ b,
                       const float* __restrict__ c, unsigned short* __restrict__ dst, int n4each){
    int i = blockIdx.x * 256 + threadIdx.x;
    if (i >= 3*n4each) return;
    int which = i / n4each, j = i - which*n4each;
    const float* src = which == 0 ? a : (which == 1 ? b : c);
    float4 v = ((const float4*)src)[j];
    u16x4 o = { f2b(v.x), f2b(v.y), f2b(v.z), f2b(v.w) };
    ((u16x4*)dst)[i] = o;
}

// ---------------------------------------------------------------------------
// lvl bias pre-tiled to the attn fragment layout (verified R6).
// ---------------------------------------------------------------------------
__global__ __launch_bounds__(256) void prep_bias_t(
    const int* __restrict__ cmat, const int* __restrict__ wmat,
    const float* __restrict__ mask, const float* __restrict__ ce, const float* __restrict__ we,
    unsigned short* __restrict__ lvlt)
{
    __shared__ float tab[64];
    __shared__ float mrow[64];
    const int t = threadIdx.x;
    const int blk = blockIdx.x;
    const int c8 = blk & 7, lt = (blk >> 3) & 7, b = blk >> 6;
    if (t < 64) tab[t] = (0.5f*ce[t>>3] + 0.5f*we[t&7]) * RS;
    if (t >= 64 && t < 128) mrow[t-64] = mask[b*512 + c8*64 + (t-64)] * LOG2E;
    __syncthreads();
    const int w = t >> 6, lane = t & 63, g = lane >> 4, cc = lane & 15;
    const int llb = lt*64 + w*16 + g*4;
    const int rlb = c8*64 + cc;
    unsigned short o[16];
    #pragma unroll
    for (int reg = 0; reg < 4; ++reg){
        const int* cr = cmat + ((size_t)b*512 + llb + reg)*512 + rlb;
        const int* wr = wmat + ((size_t)b*512 + llb + reg)*512 + rlb;
        #pragma unroll
        for (int i = 0; i < 4; ++i){
            int cv = cr[i*16], wv = wr[i*16];
            o[reg*4 + i] = f2b(tab[(cv<<3)|wv] + mrow[i*16 + cc]);
        }
    }
    unsigned short* dst = lvlt + ((size_t)blk*256 + t)*16;
    *(u16x8*)dst       = *(u16x8*)&o[0];
    *(u16x8*)(dst + 8) = *(u16x8*)&o[8];
}

// ---------------------------------------------------------------------------
// QKV projection (verified): Q,K -> [proj][b][h][s][d], V -> [b][h][d][s]
// ---------------------------------------------------------------------------
__global__ __launch_bounds__(256,3) void qkv_gemm(
    const unsigned short* __restrict__ Xb,
    const unsigned short* __restrict__ Wb,
    const float* __restrict__ bq, const float* __restrict__ bk, const float* __restrict__ bv,
    unsigned short* __restrict__ qkb,
    unsigned short* __restrict__ vtb)
{
    __shared__ unsigned short Ab[128*40];
    __shared__ unsigned short Bb[128*40];
    const int t = threadIdx.x;
    const int w = t >> 6, lane = t & 63, g = lane >> 4, cc = lane & 15;
    const int wm = w >> 1, wn = w & 1;
    const int m0 = blockIdx.x * 128;
    const int n0 = blockIdx.y * 128;

    const f32x4 fz = {0.f,0.f,0.f,0.f};
    f32x4 acc[4][4];
    #pragma unroll
    for (int i = 0; i < 4; ++i)
        #pragma unroll
        for (int j = 0; j < 4; ++j) acc[i][j] = fz;

    u16x8 pa[2], pb[2];
    #pragma unroll
    for (int r = 0; r < 2; ++r){
        int chunk = t + r*256; int row = chunk >> 2; int ch = chunk & 3;
        pa[r] = *(const u16x8*)(Xb + (size_t)(m0+row)*768 + ch*8);
        pb[r] = *(const u16x8*)(Wb + (size_t)(n0+row)*768 + ch*8);
    }
    for (int k0 = 0; k0 < 768; k0 += 32){
        __syncthreads();
        #pragma unroll
        for (int r = 0; r < 2; ++r){
            int chunk = t + r*256; int row = chunk >> 2; int ch = chunk & 3;
            *(u16x8*)&Ab[row*40 + ch*8] = pa[r];
            *(u16x8*)&Bb[row*40 + ch*8] = pb[r];
        }
        __syncthreads();
        if (k0 + 32 < 768){
            #pragma unroll
            for (int r = 0; r < 2; ++r){
                int chunk = t + r*256; int row = chunk >> 2; int ch = chunk & 3;
                pa[r] = *(const u16x8*)(Xb + (size_t)(m0+row)*768 + (k0+32) + ch*8);
                pb[r] = *(const u16x8*)(Wb + (size_t)(n0+row)*768 + (k0+32) + ch*8);
            }
        }
        bf8_t af[4], bfr[4];
        #pragma unroll
        for (int mf = 0; mf < 4; ++mf)
            af[mf] = *(const bf8_t*)&Ab[(wm*64 + mf*16 + cc)*40 + g*8];
        #pragma unroll
        for (int nf = 0; nf < 4; ++nf)
            bfr[nf] = *(const bf8_t*)&Bb[(wn*64 + nf*16 + cc)*40 + g*8];
        #pragma unroll
        for (int mf = 0; mf < 4; ++mf)
            #pragma unroll
            for (int nf = 0; nf < 4; ++nf)
                acc[mf][nf] = __builtin_amdgcn_mfma_f32_16x16x32_bf16(af[mf], bfr[nf], acc[mf][nf], 0,0,0);
    }

    const int b  = m0 >> 9;
    const int s0 = (m0 & 511) + wm*64;
    const int nbase = n0 + wn*64;
    const int proj = nbase / 768;
    const int nin0 = nbase % 768;
    const float* bias = proj == 0 ? bq : (proj == 1 ? bk : bv);
    #pragma unroll
    for (int nf = 0; nf < 4; ++nf){
        int nin = nin0 + nf*16 + cc;
        int h = nin >> 6, d = nin & 63;
        float bvv = bias[nin];
        #pragma unroll
        for (int mf = 0; mf < 4; ++mf){
            int s = s0 + mf*16 + g*4;
            if (proj < 2){
                unsigned short* base = qkb + (((((size_t)proj*Bv + b)*Hv + h)*Sv + s)*Dv + d);
                #pragma unroll
                for (int r2 = 0; r2 < 4; ++r2)
                    base[(size_t)r2*Dv] = f2b(acc[mf][nf][r2] + bvv);
            } else {
                u16x4 o = { f2b(acc[mf][nf][0]+bvv), f2b(acc[mf][nf][1]+bvv),
                            f2b(acc[mf][nf][2]+bvv), f2b(acc[mf][nf][3]+bvv) };
                *(u16x4*)(vtb + ((((size_t)b*Hv + h)*Dv + d)*Sv + s)) = o;
            }
        }
    }
}

// ---------------------------------------------------------------------------
// Fused attention v8 = R6 skeleton (des in LDS) + R7's shared T1/T2 d-frags
// + double-buffered V so ALL next-chunk staging issues at one point (post-B3)
// and drains at a single barrier: 2 barriers/chunk, no naked latency.
// t1c f32 / t2c bf16, [rl][ll] stride 68, vectorized gathers.
// LDS 73.5KB -> 2 blocks/CU.
// ---------------------------------------------------------------------------
__global__ __launch_bounds__(256,2) void attn(
    const unsigned short* __restrict__ qkb,
    const unsigned short* __restrict__ vtb,
    const unsigned short* __restrict__ deb,    // [1024][64] bf16 (row 1023 = pad)
    const unsigned short* __restrict__ lvlt,   // fragment-tiled lvl bias
    float* __restrict__ out)
{
    __shared__ __align__(16) unsigned short sm[37632];
    unsigned short* ks   = sm;                      // [64][64] swz    8192 B
    unsigned short* vsq  = sm + 4096;               // 2x [64][64] swz 16384 B
    unsigned short* P    = sm + 12288;              // [64][64] swz    8192 B
    unsigned short* des  = sm + 16384;              // [128][64] swz  16384 B
    float*          t1c  = (float*)(sm + 24576);    // [64][68] f32   17408 B
    unsigned short* t2c  = sm + 33280;              // [64][68] bf16   8704 B

    const int t = threadIdx.x, w = t >> 6, lane = t & 63, g = lane >> 4, cc = lane & 15;
    const int lr8 = lane >> 3, lc8 = lane & 7;

    // b-based XCD remap: all blocks of batch b on XCD b%8
    const int wg = blockIdx.x;
    const int xcd = wg & 7, inner = wg >> 3;
    const int b  = ((inner & 1) << 3) | xcd;
    const int r2 = inner >> 1;
    const int h  = r2 % 12, lt = r2 / 12;
    const int l0 = lt * 64;

    const unsigned short* qp = qkb + ((((size_t)0*Bv + b)*Hv + h)*Sv + l0)*Dv;
    const unsigned short* kp = qkb + ((((size_t)1*Bv + b)*Hv + h)*Sv)*Dv;
    const unsigned short* vp = vtb + (((size_t)b*Hv + h)*Dv)*Sv;
    const unsigned short* lvbase = lvlt + (((size_t)b*8 + lt)*8)*256*16 + (size_t)t*16;

    const f32x4 fz = {0.f,0.f,0.f,0.f};
    const int llb = w*16 + g*4;
    const int R   = 3 - w;                 // T2 rl-block handled by this wave
    const int rl2b = R*16 + g*4;

    auto stage_k = [&](int r0){
        #pragma unroll
        for (int j = 0; j < 2; ++j){
            int row = w*16 + j*8 + lr8;
            int ch  = lc8 ^ (row & 7);
            gload16(kp + (size_t)(r0 + row)*64 + ch*8, ks + w*1024 + j*512);
        }
    };
    auto stage_de = [&](int r0){
        const int base = l0 - r0 + 448;
        #pragma unroll
        for (int j = 0; j < 4; ++j){
            int row = w*32 + j*8 + lr8;
            int gr = base + row; if (gr > 1022) gr = 1022;
            int ch  = lc8 ^ (row & 7);
            gload16(deb + (size_t)gr*64 + ch*8, des + w*2048 + j*512);
        }
    };
    auto stage_v = [&](int r0, unsigned short* vdst){
        #pragma unroll
        for (int j = 0; j < 2; ++j){
            int row = w*16 + j*8 + lr8;
            int ch  = lc8 ^ (row & 7);
            gload16(vp + (size_t)row*512 + r0 + ch*8, vdst + w*1024 + j*512);
        }
    };

    // ---- prologue: Q frags straight from global; stage chunk-0 K/DE/V
    bf8_t qf0, qf1;
    {
        int qrow = w*16 + cc;
        qf0 = *(const bf8_t*)(qp + (size_t)qrow*64 + g*8);
        qf1 = *(const bf8_t*)(qp + (size_t)qrow*64 + (g+4)*8);
    }
    stage_k(0); stage_de(0); stage_v(0, vsq);
    __syncthreads();

    float l_run[4] = {0.f,0.f,0.f,0.f};
    f32x4 ctx[4] = {fz,fz,fz,fz};

    for (int c8 = 0; c8 < 8; ++c8){
        const int r0 = c8 * 64;
        unsigned short* vcur = vsq + (c8 & 1) * 4096;
        unsigned short* vnxt = vsq + ((c8 + 1) & 1) * 4096;

        // lvl fragment tile (global; latency hidden under MFMA phase)
        u16x8 lva = *(const u16x8*)(lvbase + (size_t)c8*256*16);
        u16x8 lvb = *(const u16x8*)(lvbase + (size_t)c8*256*16 + 8);

        // ---- MFMA phase ----
        __builtin_amdgcn_s_setprio(1);
        f32x4 accs[4];
        bf8_t kf0, kf1;
        #pragma unroll
        for (int i = 0; i < 4; ++i){                    // S = Q K^T
            int row = i*16 + cc;
            bf8_t b0 = *(const bf8_t*)&ks[row*64 + ((g       ^ (row & 7))*8)];
            bf8_t b1 = *(const bf8_t*)&ks[row*64 + (((g + 4) ^ (row & 7))*8)];
            if (i == R){ kf0 = b0; kf1 = b1; }          // K rows of block 3-w
            f32x4 a = fz;
            a = __builtin_amdgcn_mfma_f32_16x16x32_bf16(qf0, b0, a, 0,0,0);
            a = __builtin_amdgcn_mfma_f32_16x16x32_bf16(qf1, b1, a, 0,0,0);
            accs[i] = a;
        }
        #pragma unroll
        for (int i = 0; i < 5; ++i){                    // band: T1 + T2, shared d-frags
            int jrow = (w + i)*16 + cc;                 // des row 0..127
            bf8_t d0 = *(const bf8_t*)&des[jrow*64 + ((g       ^ (jrow & 7))*8)];
            bf8_t d1 = *(const bf8_t*)&des[jrow*64 + (((g + 4) ^ (jrow & 7))*8)];
            f32x4 a1 = fz, a2 = fz;
            a1 = __builtin_amdgcn_mfma_f32_16x16x32_bf16(qf0, d0, a1, 0,0,0);
            a1 = __builtin_amdgcn_mfma_f32_16x16x32_bf16(qf1, d1, a1, 0,0,0);
            a2 = __builtin_amdgcn_mfma_f32_16x16x32_bf16(kf0, d0, a2, 0,0,0);
            a2 = __builtin_amdgcn_mfma_f32_16x16x32_bf16(kf1, d1, a2, 0,0,0);
            #pragma unroll
            for (int reg = 0; reg < 4; ++reg){
                int rl1 = 4*g + reg - 16*i - cc + 63;   // T1 -> t1c[rl1][ll]
                if (rl1 >= 0 && rl1 < 64) t1c[rl1*68 + llb + reg] = a1[reg];
                int ll2 = 4*g + reg + 16*i + cc - 15;   // T2 -> t2c[rl2b+reg][ll2]
                if (ll2 >= 0 && ll2 < 64) t2c[(rl2b + reg)*68 + ll2] = f2b(a2[reg]);
            }
        }
        __builtin_amdgcn_s_setprio(0);
        __syncthreads();                                // B3: bands visible; ks/des dead

        // issue ALL next-chunk staging here; lands during epilogue+PV
        if (c8 < 7){ stage_k(r0 + 64); stage_de(r0 + 64); stage_v(r0 + 64, vnxt); }

        // ---- epilogue: vector band gathers, combine, exp2, P ----
        f32x4 t1v4[4];
        u16x4 t2v4[4];
        #pragma unroll
        for (int i = 0; i < 4; ++i){
            t1v4[i] = *(const f32x4*)&t1c[(16*i + cc)*68 + llb];
            t2v4[i] = *(const u16x4*)&t2c[(16*i + cc)*68 + llb];
        }
        #pragma unroll
        for (int reg = 0; reg < 4; ++reg){
            int ll = llb + reg;
            float ps = 0.f;
            #pragma unroll
            for (int i = 0; i < 4; ++i){
                float lvv = b2f(reg < 2 ? (unsigned short)lva[reg*4 + i]
                                        : (unsigned short)lvb[(reg-2)*4 + i]);
                float sv = (accs[i][reg] + t1v4[i][reg] + b2f((unsigned short)t2v4[i][reg])) * RS + lvv;
                float p = __builtin_amdgcn_exp2f(sv);
                ps += p;
                int rl = i*16 + cc;
                P[ll*64 + (((rl >> 3) ^ (ll & 7)) << 3) + (rl & 7)] = f2b(p);
            }
            ps += __shfl_xor(ps, 1); ps += __shfl_xor(ps, 2);
            ps += __shfl_xor(ps, 4); ps += __shfl_xor(ps, 8);
            l_run[reg] += ps;
        }

        // ---- PV ----
        __builtin_amdgcn_s_setprio(1);
        #pragma unroll
        for (int kh = 0; kh < 2; ++kh){
            int prow = w*16 + cc;
            bf8_t pf = *(const bf8_t*)&P[prow*64 + (((g + 4*kh) ^ (prow & 7)) << 3)];
            #pragma unroll
            for (int nf = 0; nf < 4; ++nf){
                int vr = nf*16 + cc;
                bf8_t vf = *(const bf8_t*)&vcur[vr*64 + (((g + 4*kh) ^ (vr & 7))*8)];
                ctx[nf] = __builtin_amdgcn_mfma_f32_16x16x32_bf16(pf, vf, ctx[nf], 0,0,0);
            }
        }
        __builtin_amdgcn_s_setprio(0);

        if (c8 < 7)
            __syncthreads();   // B1: drains staged K/DE/V; protects ks/des/t1c/t2c
    }

    #pragma unroll
    for (int nf = 0; nf < 4; ++nf){
        #pragma unroll
        for (int reg = 0; reg < 4; ++reg){
            int ll = llb + reg;
            out[((size_t)b*Sv + l0 + ll)*HIDv + h*64 + nf*16 + cc] = ctx[nf][reg] / l_run[reg];
        }
    }
}

extern "C" void kernel_launch(void* const* d_in, const int* in_sizes, int n_in,
                              void* d_out, int out_size, void* d_ws, size_t ws_size,
                              hipStream_t stream)
{
    const float* hs   = (const float*)d_in[0];
    const float* mask = (const float*)d_in[1];
    const int*   cmat = (const int*)  d_in[2];
    const int*   wmat = (const int*)  d_in[3];
    const float* Wq   = (const float*)d_in[4];
    const float* bq   = (const float*)d_in[5];
    const float* Wk   = (const float*)d_in[6];
    const float* bk   = (const float*)d_in[7];
    const float* Wv   = (const float*)d_in[8];
    const float* bv   = (const float*)d_in[9];
    const float* de   = (const float*)d_in[10];
    const float* ce   = (const float*)d_in[11];
    const float* we   = (const float*)d_in[12];
    float* out = (float*)d_out;

    unsigned short* Xb   = (unsigned short*)d_ws;        // 8192*768
    unsigned short* Wb   = Xb   + 6291456;               // 2304*768
    unsigned short* deb  = Wb   + 1769472;               // 1023*64 (+ pad)
    unsigned short* qkb  = deb  + 65536;                 // 2*16*12*512*64
    unsigned short* vtb  = qkb  + 12582912;              // 16*12*64*512
    unsigned short* lvlt = vtb  + 6291456;               // 1024*256*16

    cvt_bf16<<<2048, 256, 0, stream>>>(hs, Xb, 1572864);
    cvt_w3<<<1728, 256, 0, stream>>>(Wq, Wk, Wv, Wb, 147456);
    cvt_bf16<<<64,   256, 0, stream>>>(de, deb, 16368);
    prep_bias_t<<<1024, 256, 0, stream>>>(cmat, wmat, mask, ce, we, lvlt);

    qkv_gemm<<<dim3(64, 18), 256, 0, stream>>>(Xb, Wb, bq, bk, bv, qkb, vtb);
    attn<<<1536, 256, 0, stream>>>(qkb, vtb, deb, lvlt, out);
}

// Round 9
// 135.740 us; speedup vs baseline: 1.2654x; 1.0704x over previous
//
#include <hip/hip_runtime.h>
#include <stdint.h>

#define Bv 16
#define Sv 512
#define Hv 12
#define Dv 64
#define HIDv 768

typedef __attribute__((ext_vector_type(8))) short bf8_t;
typedef __attribute__((ext_vector_type(4))) float f32x4;
typedef __attribute__((ext_vector_type(8))) unsigned short u16x8;
typedef __attribute__((ext_vector_type(4))) unsigned short u16x4;

__device__ __forceinline__ float b2f(unsigned short u){
    union { unsigned int i; float f; } x; x.i = ((unsigned int)u) << 16; return x.f;
}
__device__ __forceinline__ unsigned short f2b(float f){
    union { float f; unsigned int i; } x; x.f = f;
    unsigned int r = x.i + 0x7fff + ((x.i >> 16) & 1);
    return (unsigned short)(r >> 16);
}
__device__ __forceinline__ void gload16(const unsigned short* g, unsigned short* l){
    __builtin_amdgcn_global_load_lds(
        (const __attribute__((address_space(1))) void*)g,
        (__attribute__((address_space(3))) void*)l, 16, 0, 0);
}

#define RS 0.18033688f          /* 0.125 * log2(e) */
#define LOG2E 1.44269504f

// ---------------------------------------------------------------------------
__global__ void cvt_bf16(const float* __restrict__ src, unsigned short* __restrict__ dst, int n4){
    int i = blockIdx.x * 256 + threadIdx.x;
    int stride = gridDim.x * 256;
    for (; i < n4; i += stride){
        float4 v = ((const float4*)src)[i];
        u16x4 o = { f2b(v.x), f2b(v.y), f2b(v.z), f2b(v.w) };
        ((u16x4*)dst)[i] = o;
    }
}

__global__ void cvt_w3(const float* __restrict__ a, const float* __restrict__ b,
                       const float* __restrict__ c, unsigned short* __restrict__ dst, int n4each){
    int i = blockIdx.x * 256 + threadIdx.x;
    if (i >= 3*n4each) return;
    int which = i / n4each, j = i - which*n4each;
    const float* src = which == 0 ? a : (which == 1 ? b : c);
    float4 v = ((const float4*)src)[j];
    u16x4 o = { f2b(v.x), f2b(v.y), f2b(v.z), f2b(v.w) };
    ((u16x4*)dst)[i] = o;
}

// ---------------------------------------------------------------------------
// lvl bias pre-tiled to the SWAPPED attn fragment layout:
// block = (b*8+lt)*8 + c8; thread t=(w,g,cc); element (i,reg) at
// ll = lt*64 + w*16 + cc,  rl = c8*64 + i*16 + 4g + reg.
// ---------------------------------------------------------------------------
__global__ __launch_bounds__(256) void prep_bias_t(
    const int* __restrict__ cmat, const int* __restrict__ wmat,
    const float* __restrict__ mask, const float* __restrict__ ce, const float* __restrict__ we,
    unsigned short* __restrict__ lvlt)
{
    __shared__ float tab[64];
    const int t = threadIdx.x;
    const int blk = blockIdx.x;
    const int c8 = blk & 7, lt = (blk >> 3) & 7, b = blk >> 6;
    if (t < 64) tab[t] = (0.5f*ce[t>>3] + 0.5f*we[t&7]) * RS;
    __syncthreads();
    const int w = t >> 6, lane = t & 63, g = lane >> 4, cc = lane & 15;
    const int ll = lt*64 + w*16 + cc;
    const int* crow = cmat + ((size_t)b*512 + ll)*512;
    const int* wrow = wmat + ((size_t)b*512 + ll)*512;
    const float* mrow = mask + (size_t)b*512;
    unsigned short o[16];
    #pragma unroll
    for (int i = 0; i < 4; ++i){
        int rb = c8*64 + i*16 + 4*g;
        int4 c4 = *(const int4*)(crow + rb);
        int4 w4 = *(const int4*)(wrow + rb);
        float4 mv = *(const float4*)(mrow + rb);
        o[i*4 + 0] = f2b(tab[(c4.x<<3)|w4.x] + mv.x * LOG2E);
        o[i*4 + 1] = f2b(tab[(c4.y<<3)|w4.y] + mv.y * LOG2E);
        o[i*4 + 2] = f2b(tab[(c4.z<<3)|w4.z] + mv.z * LOG2E);
        o[i*4 + 3] = f2b(tab[(c4.w<<3)|w4.w] + mv.w * LOG2E);
    }
    unsigned short* dst = lvlt + ((size_t)blk*256 + t)*16;
    *(u16x8*)dst       = *(u16x8*)&o[0];
    *(u16x8*)(dst + 8) = *(u16x8*)&o[8];
}

// ---------------------------------------------------------------------------
// QKV projection (verified): Q,K -> [proj][b][h][s][d], V -> [b][h][d][s]
// ---------------------------------------------------------------------------
__global__ __launch_bounds__(256,3) void qkv_gemm(
    const unsigned short* __restrict__ Xb,
    const unsigned short* __restrict__ Wb,
    const float* __restrict__ bq, const float* __restrict__ bk, const float* __restrict__ bv,
    unsigned short* __restrict__ qkb,
    unsigned short* __restrict__ vtb)
{
    __shared__ unsigned short Ab[128*40];
    __shared__ unsigned short Bb[128*40];
    const int t = threadIdx.x;
    const int w = t >> 6, lane = t & 63, g = lane >> 4, cc = lane & 15;
    const int wm = w >> 1, wn = w & 1;
    const int m0 = blockIdx.x * 128;
    const int n0 = blockIdx.y * 128;

    const f32x4 fz = {0.f,0.f,0.f,0.f};
    f32x4 acc[4][4];
    #pragma unroll
    for (int i = 0; i < 4; ++i)
        #pragma unroll
        for (int j = 0; j < 4; ++j) acc[i][j] = fz;

    u16x8 pa[2], pb[2];
    #pragma unroll
    for (int r = 0; r < 2; ++r){
        int chunk = t + r*256; int row = chunk >> 2; int ch = chunk & 3;
        pa[r] = *(const u16x8*)(Xb + (size_t)(m0+row)*768 + ch*8);
        pb[r] = *(const u16x8*)(Wb + (size_t)(n0+row)*768 + ch*8);
    }
    for (int k0 = 0; k0 < 768; k0 += 32){
        __syncthreads();
        #pragma unroll
        for (int r = 0; r < 2; ++r){
            int chunk = t + r*256; int row = chunk >> 2; int ch = chunk & 3;
            *(u16x8*)&Ab[row*40 + ch*8] = pa[r];
            *(u16x8*)&Bb[row*40 + ch*8] = pb[r];
        }
        __syncthreads();
        if (k0 + 32 < 768){
            #pragma unroll
            for (int r = 0; r < 2; ++r){
                int chunk = t + r*256; int row = chunk >> 2; int ch = chunk & 3;
                pa[r] = *(const u16x8*)(Xb + (size_t)(m0+row)*768 + (k0+32) + ch*8);
                pb[r] = *(const u16x8*)(Wb + (size_t)(n0+row)*768 + (k0+32) + ch*8);
            }
        }
        bf8_t af[4], bfr[4];
        #pragma unroll
        for (int mf = 0; mf < 4; ++mf)
            af[mf] = *(const bf8_t*)&Ab[(wm*64 + mf*16 + cc)*40 + g*8];
        #pragma unroll
        for (int nf = 0; nf < 4; ++nf)
            bfr[nf] = *(const bf8_t*)&Bb[(wn*64 + nf*16 + cc)*40 + g*8];
        #pragma unroll
        for (int mf = 0; mf < 4; ++mf)
            #pragma unroll
            for (int nf = 0; nf < 4; ++nf)
                acc[mf][nf] = __builtin_amdgcn_mfma_f32_16x16x32_bf16(af[mf], bfr[nf], acc[mf][nf], 0,0,0);
    }

    const int b  = m0 >> 9;
    const int s0 = (m0 & 511) + wm*64;
    const int nbase = n0 + wn*64;
    const int proj = nbase / 768;
    const int nin0 = nbase % 768;
    const float* bias = proj == 0 ? bq : (proj == 1 ? bk : bv);
    #pragma unroll
    for (int nf = 0; nf < 4; ++nf){
        int nin = nin0 + nf*16 + cc;
        int h = nin >> 6, d = nin & 63;
        float bvv = bias[nin];
        #pragma unroll
        for (int mf = 0; mf < 4; ++mf){
            int s = s0 + mf*16 + g*4;
            if (proj < 2){
                unsigned short* base = qkb + (((((size_t)proj*Bv + b)*Hv + h)*Sv + s)*Dv + d);
                #pragma unroll
                for (int r2 = 0; r2 < 4; ++r2)
                    base[(size_t)r2*Dv] = f2b(acc[mf][nf][r2] + bvv);
            } else {
                u16x4 o = { f2b(acc[mf][nf][0]+bvv), f2b(acc[mf][nf][1]+bvv),
                            f2b(acc[mf][nf][2]+bvv), f2b(acc[mf][nf][3]+bvv) };
                *(u16x4*)(vtb + ((((size_t)b*Hv + h)*Dv + d)*Sv + s)) = o;
            }
        }
    }
}

// ---------------------------------------------------------------------------
// Fused attention v9: swapped-operand scores (C[rl][ll] -> lane owns ONE ll),
// f32 band buffers with ds_write2/ds_read2 (diagonal pair-vectorized, masked
// only at i=0/4 into +-1 garbage rows/cols), packed-u32 swizzled P (4xb64 w,
// 2xb128 r), 2-shuffle softmax sum, single-V with reg restage (T14).
// LDS 75.8KB -> 2 blocks/CU.
// ---------------------------------------------------------------------------
__global__ __launch_bounds__(256,2) void attn(
    const unsigned short* __restrict__ qkb,
    const unsigned short* __restrict__ vtb,
    const unsigned short* __restrict__ deb,    // [1024][64] bf16 (row 1023 = pad)
    const unsigned short* __restrict__ lvlt,   // fragment-tiled lvl bias
    float* __restrict__ out)
{
    __shared__ __align__(16) unsigned short sm[37904];
    unsigned short* ks  = sm;                        // [64][64] swz    8192 B
    unsigned short* vsq = sm + 4096;                 // [64][64] swz    8192 B
    unsigned short* des = sm + 8192;                 // [128][64] swz  16384 B
    float*          t1c = (float*)(sm + 16384);      // [66][68] f32   17952 B
    float*          t2c = (float*)(sm + 25360);      // [64][66] f32   16896 B
    unsigned int*   Pb  = (unsigned int*)(sm + 33808); // [64][32] u32  8192 B

    const int t = threadIdx.x, w = t >> 6, lane = t & 63, g = lane >> 4, cc = lane & 15;
    const int lr8 = lane >> 3, lc8 = lane & 7;

    // b-based XCD remap: all blocks of batch b on XCD b%8
    const int wg = blockIdx.x;
    const int xcd = wg & 7, inner = wg >> 3;
    const int b  = ((inner & 1) << 3) | xcd;
    const int r2 = inner >> 1;
    const int h  = r2 % 12, lt = r2 / 12;
    const int l0 = lt * 64;

    const unsigned short* qp = qkb + ((((size_t)0*Bv + b)*Hv + h)*Sv + l0)*Dv;
    const unsigned short* kp = qkb + ((((size_t)1*Bv + b)*Hv + h)*Sv)*Dv;
    const unsigned short* vp = vtb + (((size_t)b*Hv + h)*Dv)*Sv;
    const unsigned short* lvbase = lvlt + (((size_t)b*8 + lt)*8)*256*16 + (size_t)t*16;

    const f32x4 fz = {0.f,0.f,0.f,0.f};
    const int R   = 3 - w;               // T2 rl-block (jb range matches T1's)
    const int llm = w*16 + cc;           // lane's score/softmax/P row
    const int sw  = (cc & 7) << 2;       // P column swizzle
    const int d_t1 = cc - 4*g;           // t1 mask helper
    const int s_t2 = 4*g + cc;           // t2 mask helper

    auto stage_k = [&](int r0){
        #pragma unroll
        for (int j = 0; j < 2; ++j){
            int row = w*16 + j*8 + lr8;
            int ch  = lc8 ^ (row & 7);
            gload16(kp + (size_t)(r0 + row)*64 + ch*8, ks + w*1024 + j*512);
        }
    };
    auto stage_de = [&](int r0){
        const int base = l0 - r0 + 448;
        #pragma unroll
        for (int j = 0; j < 4; ++j){
            int row = w*32 + j*8 + lr8;
            int gr = base + row; if (gr > 1022) gr = 1022;
            int ch  = lc8 ^ (row & 7);
            gload16(deb + (size_t)gr*64 + ch*8, des + w*2048 + j*512);
        }
    };
    auto stage_v0 = [&](){
        #pragma unroll
        for (int j = 0; j < 2; ++j){
            int row = w*16 + j*8 + lr8;
            int ch  = lc8 ^ (row & 7);
            gload16(vp + (size_t)row*512 + ch*8, vsq + w*1024 + j*512);
        }
    };

    // ---- prologue: Q frags from global (B-layout == A-layout); stage chunk-0
    bf8_t qf0, qf1;
    {
        int qrow = w*16 + cc;
        qf0 = *(const bf8_t*)(qp + (size_t)qrow*64 + g*8);
        qf1 = *(const bf8_t*)(qp + (size_t)qrow*64 + (g+4)*8);
    }
    stage_k(0); stage_de(0); stage_v0();
    __syncthreads();

    float l_run = 0.f;
    f32x4 ctx[4] = {fz,fz,fz,fz};

    for (int c8 = 0; c8 < 8; ++c8){
        const int r0 = c8 * 64;
        u16x8 lva = *(const u16x8*)(lvbase + (size_t)c8*256*16);
        u16x8 lvb = *(const u16x8*)(lvbase + (size_t)c8*256*16 + 8);

        // ---- MFMA phase: swapped scores + band with write2 scatters ----
        __builtin_amdgcn_s_setprio(1);
        f32x4 accs[4];                         // C[rl][ll]: rl=i16+4g+reg, ll=llm
        bf8_t kf0, kf1;
        #pragma unroll
        for (int i = 0; i < 4; ++i){
            int row = i*16 + cc;
            bf8_t b0 = *(const bf8_t*)&ks[row*64 + ((g       ^ (row & 7))*8)];
            bf8_t b1 = *(const bf8_t*)&ks[row*64 + (((g + 4) ^ (row & 7))*8)];
            if (i == R){ kf0 = b0; kf1 = b1; }
            f32x4 a = fz;
            a = __builtin_amdgcn_mfma_f32_16x16x32_bf16(b0, qf0, a, 0,0,0);
            a = __builtin_amdgcn_mfma_f32_16x16x32_bf16(b1, qf1, a, 0,0,0);
            accs[i] = a;
        }
        #pragma unroll
        for (int i = 0; i < 5; ++i){
            int jrow = (w + i)*16 + cc;
            bf8_t d0 = *(const bf8_t*)&des[jrow*64 + ((g       ^ (jrow & 7))*8)];
            bf8_t d1 = *(const bf8_t*)&des[jrow*64 + (((g + 4) ^ (jrow & 7))*8)];
            f32x4 a1 = fz, a2 = fz;                             // a1=C[jb][ll], a2=C[rl][jb]
            a1 = __builtin_amdgcn_mfma_f32_16x16x32_bf16(d0, qf0, a1, 0,0,0);
            a1 = __builtin_amdgcn_mfma_f32_16x16x32_bf16(d1, qf1, a1, 0,0,0);
            a2 = __builtin_amdgcn_mfma_f32_16x16x32_bf16(kf0, d0, a2, 0,0,0);
            a2 = __builtin_amdgcn_mfma_f32_16x16x32_bf16(kf1, d1, a2, 0,0,0);

            // t1 scatter: row = (ll - jb + 63) + 1, col = llm; desc in reg
            {
                float* tb = t1c + (cc - 16*i - 4*g + 61)*68 + llm;
                bool mA = (i != 0 || d_t1 <= 3) && (i != 4 || d_t1 >= 3);
                bool mB = (i != 0 || d_t1 <= 1) && (i != 4 || d_t1 >= 1);
                if (mA){ tb[0]   = a1[3]; tb[68]  = a1[2]; }
                if (mB){ tb[136] = a1[1]; tb[204] = a1[0]; }
            }
            // t2 scatter: row = rl, col = (rl + jb - 63) + 1; asc (+67) in reg
            {
                float* tb = t2c + (R*16 + 4*g)*66 + (16*i + 4*g + cc - 14);
                bool mA = (i != 0 || s_t2 >= 14) && (i != 4 || s_t2 <= 14);
                bool mB = (i != 0 || s_t2 >= 12) && (i != 4 || s_t2 <= 12);
                if (mA){ tb[0]   = a2[0]; tb[67]  = a2[1]; }
                if (mB){ tb[134] = a2[2]; tb[201] = a2[3]; }
            }
        }
        __builtin_amdgcn_s_setprio(0);
        __syncthreads();                       // B3: band visible; ks/des dead

        // issue next-chunk staging: K/DE direct-to-LDS, V to registers (T14)
        u16x8 pv0, pv1;
        if (c8 < 7){
            stage_k(r0 + 64); stage_de(r0 + 64);
            int row0 = w*16 + lr8,  ch0 = lc8 ^ (row0 & 7);
            int row1 = row0 + 8,    ch1 = lc8 ^ (row1 & 7);
            pv0 = *(const u16x8*)(vp + (size_t)row0*512 + (r0+64) + ch0*8);
            pv1 = *(const u16x8*)(vp + (size_t)row1*512 + (r0+64) + ch1*8);
        }

        // ---- epilogue: read2 gathers, combine, exp2, packed P ----
        float ps = 0.f;
        #pragma unroll
        for (int i = 0; i < 4; ++i){
            const float* g1 = t1c + (i*16 + 4*g + 1)*68 + llm;
            const float* g2 = t2c + (i*16 + 4*g)*66 + llm + 1;
            float t10 = g1[0], t11 = g1[68], t12 = g1[136], t13 = g1[204];
            float t20 = g2[0], t21 = g2[66], t22 = g2[132], t23 = g2[198];
            float lv0 = b2f(i < 2 ? (unsigned short)lva[i*4+0] : (unsigned short)lvb[(i-2)*4+0]);
            float lv1 = b2f(i < 2 ? (unsigned short)lva[i*4+1] : (unsigned short)lvb[(i-2)*4+1]);
            float lv2 = b2f(i < 2 ? (unsigned short)lva[i*4+2] : (unsigned short)lvb[(i-2)*4+2]);
            float lv3 = b2f(i < 2 ? (unsigned short)lva[i*4+3] : (unsigned short)lvb[(i-2)*4+3]);
            float p0 = __builtin_amdgcn_exp2f((accs[i][0] + t10 + t20) * RS + lv0);
            float p1 = __builtin_amdgcn_exp2f((accs[i][1] + t11 + t21) * RS + lv1);
            float p2 = __builtin_amdgcn_exp2f((accs[i][2] + t12 + t22) * RS + lv2);
            float p3 = __builtin_amdgcn_exp2f((accs[i][3] + t13 + t23) * RS + lv3);
            ps += (p0 + p1) + (p2 + p3);
            unsigned int prs0 = (unsigned)f2b(p0) | ((unsigned)f2b(p1) << 16);
            unsigned int prs1 = (unsigned)f2b(p2) | ((unsigned)f2b(p3) << 16);
            uint2 pr = { prs0, prs1 };
            *(uint2*)&Pb[llm*32 + ((i*8 + 2*g) ^ sw)] = pr;
        }
        ps += __shfl_xor(ps, 16);
        ps += __shfl_xor(ps, 32);
        l_run += ps;
        __builtin_amdgcn_wave_barrier();       // keep P writes before PV reads

        // ---- PV: A = P (packed, swizzled), B = V ----
        __builtin_amdgcn_s_setprio(1);
        #pragma unroll
        for (int kh = 0; kh < 2; ++kh){
            bf8_t pf = *(const bf8_t*)&Pb[llm*32 + ((16*kh + 4*g) ^ sw)];
            #pragma unroll
            for (int nf = 0; nf < 4; ++nf){
                int vr = nf*16 + cc;
                bf8_t vf = *(const bf8_t*)&vsq[vr*64 + (((g + 4*kh) ^ (vr & 7))*8)];
                ctx[nf] = __builtin_amdgcn_mfma_f32_16x16x32_bf16(pf, vf, ctx[nf], 0,0,0);
            }
        }
        __builtin_amdgcn_s_setprio(0);

        if (c8 < 7){
            __syncthreads();                   // B1: PV done; K/DE gloads drained
            *(u16x8*)&vsq[w*1024 +       lane*8] = pv0;
            *(u16x8*)&vsq[w*1024 + 512 + lane*8] = pv1;
            __syncthreads();                   // B2: new V visible
        }
    }

    // redistribute l_run (per-cc row sums) to the ctx row layout (4g+reg)
    float linv[4];
    #pragma unroll
    for (int reg = 0; reg < 4; ++reg)
        linv[reg] = 1.0f / __shfl(l_run, 4*g + reg);

    #pragma unroll
    for (int nf = 0; nf < 4; ++nf){
        #pragma unroll
        for (int reg = 0; reg < 4; ++reg){
            int ll = w*16 + 4*g + reg;
            out[((size_t)b*Sv + l0 + ll)*HIDv + h*64 + nf*16 + cc] = ctx[nf][reg] * linv[reg];
        }
    }
}

extern "C" void kernel_launch(void* const* d_in, const int* in_sizes, int n_in,
                              void* d_out, int out_size, void* d_ws, size_t ws_size,
                              hipStream_t stream)
{
    const float* hs   = (const float*)d_in[0];
    const float* mask = (const float*)d_in[1];
    const int*   cmat = (const int*)  d_in[2];
    const int*   wmat = (const int*)  d_in[3];
    const float* Wq   = (const float*)d_in[4];
    const float* bq   = (const float*)d_in[5];
    const float* Wk   = (const float*)d_in[6];
    const float* bk   = (const float*)d_in[7];
    const float* Wv   = (const float*)d_in[8];
    const float* bv   = (const float*)d_in[9];
    const float* de   = (const float*)d_in[10];
    const float* ce   = (const float*)d_in[11];
    const float* we   = (const float*)d_in[12];
    float* out = (float*)d_out;

    unsigned short* Xb   = (unsigned short*)d_ws;        // 8192*768
    unsigned short* Wb   = Xb   + 6291456;               // 2304*768
    unsigned short* deb  = Wb   + 1769472;               // 1023*64 (+ pad)
    unsigned short* qkb  = deb  + 65536;                 // 2*16*12*512*64
    unsigned short* vtb  = qkb  + 12582912;              // 16*12*64*512
    unsigned short* lvlt = vtb  + 6291456;               // 1024*256*16

    cvt_bf16<<<2048, 256, 0, stream>>>(hs, Xb, 1572864);
    cvt_w3<<<1728, 256, 0, stream>>>(Wq, Wk, Wv, Wb, 147456);
    cvt_bf16<<<64,   256, 0, stream>>>(de, deb, 16368);
    prep_bias_t<<<1024, 256, 0, stream>>>(cmat, wmat, mask, ce, we, lvlt);

    qkv_gemm<<<dim3(64, 18), 256, 0, stream>>>(Xb, Wb, bq, bk, bv, qkb, vtb);
    attn<<<1536, 256, 0, stream>>>(qkb, vtb, deb, lvlt, out);
}